// Round 1
// baseline (814.464 us; speedup 1.0000x reference)
//
#include <hip/hip_runtime.h>
#include <math.h>

#define B_ 16
#define P_ 25
#define S_ 1024
#define D_ 128
#define H_ 8
#define DH_ 16
#define DFF_ 512
#define SIGMA_ 0.1f

typedef float f4 __attribute__((ext_vector_type(4)));

// out layout (floats):
// r_:0  z:51200  pred:102400  w:102800  K_res:103200  V_res:52532000  I_new:104960800

// ---------------- K1: q,k,v projections ----------------
__global__ __launch_bounds__(128) void qkv_kernel(
    const float* __restrict__ x, const float* __restrict__ Wq,
    const float* __restrict__ Wk, const float* __restrict__ Wv,
    const float* __restrict__ eps_k, const float* __restrict__ eps_v,
    float* __restrict__ q, float* __restrict__ k, float* __restrict__ v) {
  int bp = blockIdx.x;  // 0..399
  int d = threadIdx.x;  // 0..127
  __shared__ float xs[D_];
  xs[d] = x[bp * D_ + d];
  __syncthreads();
  float accq = 0.f, acck = 0.f, accv = 0.f;
  for (int i = 0; i < D_; ++i) {
    float xv = xs[i];
    accq += xv * Wq[i * D_ + d];
    acck += xv * Wk[i * D_ + d];
    accv += xv * Wv[i * D_ + d];
  }
  q[bp * D_ + d] = accq;
  k[bp * D_ + d] = acck + SIGMA_ * eps_k[bp * D_ + d];
  v[bp * D_ + d] = accv + SIGMA_ * eps_v[bp * D_ + d];
}

// ---------------- K2: attention (flash-decode, float4 lanes, 2 rows/wave) ----
// Lane layout: row = lane>>5 (2 s-rows per wave), lr = lane&31 covers float4
// index lr of the 128-float row; head = lr>>2 (4 lanes per head, dh=16).
// Score reduce = 2 shfl_xor (1,2) within the quad.  16 partial slots
// (8 waves x 2 rows) merged at the end.
__global__ __launch_bounds__(512) void attn_kernel(
    const float* __restrict__ q, const float* __restrict__ kn,
    const float* __restrict__ vn, const float* __restrict__ K,
    const float* __restrict__ V, const int* __restrict__ tptr,
    float* __restrict__ ctx) {
  int bp = blockIdx.x;  // 0..399
  int t = tptr[0];
  int tid = threadIdx.x;
  int wave = tid >> 6;   // 0..7
  int lane = tid & 63;
  int row = lane >> 5;   // 0..1
  int lr = lane & 31;    // float4 index within row
  int w16 = wave * 2 + row;  // partial slot 0..15
  __shared__ __align__(16) float qs[D_];
  __shared__ __align__(16) float accs[16][D_];
  __shared__ float ms[16][H_];
  __shared__ float ls[16][H_];
  if (tid < D_) qs[tid] = q[bp * D_ + tid] * 0.25f;  // 1/sqrt(DH)
  __syncthreads();
  const f4* Kb = (const f4*)(K + (size_t)bp * S_ * D_);
  const f4* Vb = (const f4*)(V + (size_t)bp * S_ * D_);
  const f4* kn4 = (const f4*)(kn + bp * D_);
  const f4* vn4 = (const f4*)(vn + bp * D_);
  f4 qv = *(const f4*)(qs + 4 * lr);
  float m = -1e30f, l = 0.f;
  f4 acc = {0.f, 0.f, 0.f, 0.f};
  const int RD4 = D_ / 4;  // 32 float4 per row
  for (int s = w16; s <= t; s += 16) {
    const f4 *Kr, *Vr;
    if (s == t) { Kr = kn4; Vr = vn4; }
    else        { Kr = Kb + (size_t)s * RD4; Vr = Vb + (size_t)s * RD4; }
    f4 kk = Kr[lr];
    f4 vv = Vr[lr];
    float p = qv.x * kk.x + qv.y * kk.y + qv.z * kk.z + qv.w * kk.w;
    p += __shfl_xor(p, 1);
    p += __shfl_xor(p, 2);  // all 4 lanes of quad hold score for head lr>>2
    float mnew = fmaxf(m, p);
    float scale = expf(m - mnew);
    float e = expf(p - mnew);
    l = l * scale + e;
    acc.x = acc.x * scale + e * vv.x;
    acc.y = acc.y * scale + e * vv.y;
    acc.z = acc.z * scale + e * vv.z;
    acc.w = acc.w * scale + e * vv.w;
    m = mnew;
  }
  *(f4*)(&accs[w16][4 * lr]) = acc;
  if ((lr & 3) == 0) { ms[w16][lr >> 2] = m; ls[w16][lr >> 2] = l; }
  __syncthreads();
  if (tid < D_) {
    int h = tid >> 4;
    float mg = -1e30f;
    for (int w2 = 0; w2 < 16; ++w2) mg = fmaxf(mg, ms[w2][h]);
    float L = 0.f, C = 0.f;
    for (int w2 = 0; w2 < 16; ++w2) {
      float sc = expf(ms[w2][h] - mg);
      L += ls[w2][h] * sc;
      C += accs[w2][tid] * sc;
    }
    ctx[bp * D_ + tid] = C / L;
  }
}

// ---------------- K3: Wo + eps_z, FFN, pred (all 512 threads in every dot) --
__global__ __launch_bounds__(512) void head_kernel(
    const float* __restrict__ ctx, const float* __restrict__ Wo,
    const float* __restrict__ eps_z, const float* __restrict__ W1,
    const float* __restrict__ b1, const float* __restrict__ W2,
    const float* __restrict__ b2, const float* __restrict__ Wout,
    const float* __restrict__ bout, float* __restrict__ out_r,
    float* __restrict__ out_z, float* __restrict__ out_pred) {
  int bp = blockIdx.x;
  int tid = threadIdx.x;
  int d = tid & 127;   // output dim
  int qq = tid >> 7;   // quarter 0..3
  __shared__ float cs[D_];
  __shared__ float zs[D_];
  __shared__ float as_[DFF_];
  __shared__ float rs[D_];
  __shared__ float part[4][D_];
  if (tid < D_) cs[tid] = ctx[bp * D_ + tid];
  __syncthreads();
  {  // z = ctx @ Wo : quarter-split over i, 32 iters/thread
    float acc = 0.f;
    int i0 = qq * 32;
    for (int i = i0; i < i0 + 32; ++i) acc += cs[i] * Wo[i * D_ + d];
    part[qq][d] = acc;
  }
  __syncthreads();
  if (tid < D_) {
    float z = part[0][tid] + part[1][tid] + part[2][tid] + part[3][tid] +
              SIGMA_ * eps_z[bp * D_ + tid];
    zs[tid] = z;
    out_z[bp * D_ + tid] = z;
  }
  __syncthreads();
  {  // a = relu(z @ W1 + b1) : all 512 threads, 128 iters
    float acc = b1[tid];
    for (int i = 0; i < D_; ++i) acc += zs[i] * W1[i * DFF_ + tid];
    as_[tid] = fmaxf(acc, 0.f);
  }
  __syncthreads();
  {  // r = a @ W2 + b2 : quarter-split over j, 128 iters/thread (was 512)
    float acc = 0.f;
    int j0 = qq * 128;
    for (int j = j0; j < j0 + 128; ++j) acc += as_[j] * W2[j * D_ + d];
    part[qq][d] = acc;
  }
  __syncthreads();
  if (tid < D_) {
    float r = part[0][tid] + part[1][tid] + part[2][tid] + part[3][tid] + b2[tid];
    rs[tid] = r;
    out_r[bp * D_ + tid] = r;
  }
  __syncthreads();
  if (tid < 64) {
    float acc = rs[tid] * Wout[tid] + rs[tid + 64] * Wout[tid + 64];
    acc += __shfl_xor(acc, 1);
    acc += __shfl_xor(acc, 2);
    acc += __shfl_xor(acc, 4);
    acc += __shfl_xor(acc, 8);
    acc += __shfl_xor(acc, 16);
    acc += __shfl_xor(acc, 32);
    if (tid == 0) out_pred[bp] = acc + bout[0];
  }
}

// ---------------- K4: weights + threefry categorical sampling ----------------
__device__ inline unsigned rotl_(unsigned x, int r) {
  return (x << r) | (x >> (32 - r));
}

__device__ inline void threefry2x32_(unsigned x0, unsigned x1, unsigned& o0,
                                     unsigned& o1) {
  const unsigned k0 = 0u, k1 = 42u;
  const unsigned k2 = k0 ^ k1 ^ 0x1BD11BDAu;
  x0 += k0; x1 += k1;
#define RND_(r) { x0 += x1; x1 = rotl_(x1, r); x1 ^= x0; }
  RND_(13) RND_(15) RND_(26) RND_(6)   x0 += k1; x1 += k2 + 1u;
  RND_(17) RND_(29) RND_(16) RND_(24)  x0 += k2; x1 += k0 + 2u;
  RND_(13) RND_(15) RND_(26) RND_(6)   x0 += k0; x1 += k1 + 3u;
  RND_(17) RND_(29) RND_(16) RND_(24)  x0 += k1; x1 += k2 + 4u;
  RND_(13) RND_(15) RND_(26) RND_(6)   x0 += k2; x1 += k0 + 5u;
#undef RND_
  o0 = x0; o1 = x1;
}

__device__ inline float gumbel_at_(int n) {
  unsigned o0, o1;
  threefry2x32_(0u, (unsigned)n, o0, o1);
  unsigned bits = o0 ^ o1;
  unsigned fb = (bits >> 9) | 0x3f800000u;
  float f = __uint_as_float(fb) - 1.0f;
  const float tiny = 1.1754944e-38f;
  float u = fmaxf(tiny, f * (1.0f - tiny) + tiny);
  return -logf(-logf(u));
}

__global__ __launch_bounds__(64) void sample_kernel(
    const float* __restrict__ pred, const float* __restrict__ y,
    float* __restrict__ out_w, int* __restrict__ idx) {
  int b = blockIdx.x;  // 0..15
  int tid = threadIdx.x;
  __shared__ float lw[P_];
  __shared__ float logits[P_];
  __shared__ float red[2];
  if (tid < P_) {
    float mu = y[b * 4] - pred[b * P_ + tid];
    lw[tid] = -0.25f * (mu * mu);  // -0.5*OMEGA
  }
  __syncthreads();
  if (tid == 0) {
    float mn = lw[0];
    for (int p = 1; p < P_; ++p) mn = fminf(mn, lw[p]);
    red[0] = mn;
  }
  __syncthreads();
  if (tid < P_) lw[tid] = expf(lw[tid] - red[0]);
  __syncthreads();
  if (tid == 0) {
    float s = 0.f;
    for (int p = 0; p < P_; ++p) s += lw[p];
    red[1] = s;
  }
  __syncthreads();
  if (tid < P_) {
    float wn = lw[tid] / red[1];
    out_w[b * P_ + tid] = wn;
    logits[tid] = logf(wn + 1e-10f);
  }
  __syncthreads();
  if (tid < P_) {
    float best = -1e30f;
    int bestj = 0;
    for (int j = 0; j < P_; ++j) {
      int n = (b * P_ + tid) * P_ + j;
      float val = gumbel_at_(n) + logits[j];
      if (val > best) { best = val; bestj = j; }  // first-index tie-break
    }
    idx[b * P_ + tid] = bestj;
  }
}

// ---------------- K5: gather K_res / V_res (nontemporal streaming stores) ----
__global__ __launch_bounds__(256) void gather_kernel(
    const float* __restrict__ K, const float* __restrict__ V,
    const float* __restrict__ kn, const float* __restrict__ vn,
    const int* __restrict__ idx, const int* __restrict__ tptr,
    float* __restrict__ outK, float* __restrict__ outV) {
  const int CH = 4;                       // chunks per row
  const int F4 = (S_ * D_ / 4) / CH;      // 8192 float4 per chunk
  int bid = blockIdx.x;                   // 0..3199
  int tv = bid / (B_ * P_ * CH);
  int rem = bid - tv * (B_ * P_ * CH);
  int bp = rem / CH;
  int chunk = rem - bp * CH;
  int b = bp / P_;
  int j = idx[bp];
  int t = tptr[0];
  const float* src = (tv == 0 ? K : V) + (size_t)(b * P_ + j) * (S_ * D_);
  const f4* sub = (const f4*)((tv == 0 ? kn : vn) + (b * P_ + j) * D_);
  float* dst = (tv == 0 ? outK : outV) + (size_t)bp * (S_ * D_);
  const f4* src4 = (const f4*)src;
  f4* dst4 = (f4*)dst;
  int base = chunk * F4;
  int tlo = t * (D_ / 4);
  for (int i = base + threadIdx.x; i < base + F4; i += 256) {
    f4 val;
    if (i >= tlo && i < tlo + D_ / 4) val = sub[i - tlo];
    else                              val = src4[i];
    __builtin_nontemporal_store(val, dst4 + i);  // streamed, never re-read
  }
}

// ---------------- K6: I_new (ints written as float values) ----------------
__global__ __launch_bounds__(256) void inew_kernel(
    const int* __restrict__ I, const int* __restrict__ idx,
    const int* __restrict__ tptr, float* __restrict__ outI) {
  int bp = blockIdx.x;
  int b = bp / P_;
  int j = idx[bp];
  int t = tptr[0];
  const int* src = I + (b * P_ + j) * S_;
  float* dst = outI + bp * S_;
  for (int s = threadIdx.x; s < S_; s += 256) {
    int val = (s == t) ? j : src[s];
    __builtin_nontemporal_store((float)val, dst + s);
  }
}

extern "C" void kernel_launch(void* const* d_in, const int* in_sizes, int n_in,
                              void* d_out, int out_size, void* d_ws,
                              size_t ws_size, hipStream_t stream) {
  const float* x     = (const float*)d_in[0];
  const float* y     = (const float*)d_in[1];
  const float* K     = (const float*)d_in[2];
  const float* V     = (const float*)d_in[3];
  const int*   I     = (const int*)d_in[5];
  const float* Wq    = (const float*)d_in[6];
  const float* Wk    = (const float*)d_in[7];
  const float* Wv    = (const float*)d_in[8];
  const float* Wo    = (const float*)d_in[9];
  const float* W1    = (const float*)d_in[10];
  const float* b1    = (const float*)d_in[11];
  const float* W2    = (const float*)d_in[12];
  const float* b2    = (const float*)d_in[13];
  const float* Wout  = (const float*)d_in[14];
  const float* bout  = (const float*)d_in[15];
  const float* eps_k = (const float*)d_in[16];
  const float* eps_v = (const float*)d_in[17];
  const float* eps_z = (const float*)d_in[18];
  const int*   tptr  = (const int*)d_in[19];

  float* out      = (float*)d_out;
  float* out_r    = out;
  float* out_z    = out + 51200;
  float* out_pred = out + 102400;
  float* out_w    = out + 102800;
  float* outK     = out + 103200;
  float* outV     = outK + (size_t)52428800;
  float* outI     = outV + (size_t)52428800;

  float* ws  = (float*)d_ws;
  float* q   = ws;
  float* k   = ws + 51200;
  float* v   = ws + 102400;
  float* ctx = ws + 153600;
  int*   idx = (int*)(ws + 204800);

  qkv_kernel<<<B_ * P_, 128, 0, stream>>>(x, Wq, Wk, Wv, eps_k, eps_v, q, k, v);
  attn_kernel<<<B_ * P_, 512, 0, stream>>>(q, k, v, K, V, tptr, ctx);
  head_kernel<<<B_ * P_, 512, 0, stream>>>(ctx, Wo, eps_z, W1, b1, W2, b2, Wout,
                                           bout, out_r, out_z, out_pred);
  sample_kernel<<<B_, 64, 0, stream>>>(out_pred, y, out_w, idx);
  gather_kernel<<<B_ * P_ * 4 * 2, 256, 0, stream>>>(K, V, k, v, idx, tptr,
                                                     outK, outV);
  inew_kernel<<<B_ * P_, 256, 0, stream>>>(I, idx, tptr, outI);
}

// Round 2
// 779.262 us; speedup vs baseline: 1.0452x; 1.0452x over previous
//
#include <hip/hip_runtime.h>
#include <math.h>

#define B_ 16
#define P_ 25
#define S_ 1024
#define D_ 128
#define H_ 8
#define DH_ 16
#define DFF_ 512
#define SIGMA_ 0.1f

typedef float f4 __attribute__((ext_vector_type(4)));

// out layout (floats):
// r_:0  z:51200  pred:102400  w:102800  K_res:103200  V_res:52532000  I_new:104960800

// ---------------- K1: fused qkv + attention + head (block = one bp) --------
// Phases (block-local deps only, __syncthreads between):
//   1. xs <- x[bp]
//   2. q,k,v projections (3 x 128-wide dots, one quarter of threads each)
//   3. flash-decode attn over s<=t (16 row-slots, float4 lanes, 2 rows/wave)
//   4. slot merge -> ctx (LDS only, never leaves the block)
//   5. Wo + eps_z -> z ; relu(z@W1+b1) ; @W2+b2 -> r ; r@Wout -> pred
__global__ __launch_bounds__(512) void fused_kernel(
    const float* __restrict__ x, const float* __restrict__ Wq,
    const float* __restrict__ Wk, const float* __restrict__ Wv,
    const float* __restrict__ eps_k, const float* __restrict__ eps_v,
    const float* __restrict__ K, const float* __restrict__ V,
    const int* __restrict__ tptr, const float* __restrict__ Wo,
    const float* __restrict__ eps_z, const float* __restrict__ W1,
    const float* __restrict__ b1, const float* __restrict__ W2,
    const float* __restrict__ b2, const float* __restrict__ Wout,
    const float* __restrict__ bout, float* __restrict__ kw,
    float* __restrict__ vw, float* __restrict__ out_r,
    float* __restrict__ out_z, float* __restrict__ out_pred) {
  int bp = blockIdx.x;  // 0..399
  int tid = threadIdx.x;
  int t = tptr[0];

  __shared__ __align__(16) float xs[D_];
  __shared__ __align__(16) float qs[D_];   // pre-scaled by 1/sqrt(DH)
  __shared__ __align__(16) float ks[D_];
  __shared__ __align__(16) float vs[D_];
  __shared__ __align__(16) float accs[16][D_];
  __shared__ float ms[16][H_];
  __shared__ float ls[16][H_];
  __shared__ float cs[D_];
  __shared__ float zs[D_];
  __shared__ float as_[DFF_];
  __shared__ float rs[D_];
  __shared__ float part[4][D_];

  if (tid < D_) xs[tid] = x[bp * D_ + tid];
  __syncthreads();

  // ---- qkv: mat = tid>>7 in {0,1,2}, d = tid&127; 4th quarter idles ----
  {
    int mat = tid >> 7;
    int d = tid & 127;
    if (mat < 3) {
      const float* W = (mat == 0) ? Wq : (mat == 1) ? Wk : Wv;
      float acc = 0.f;
      for (int i = 0; i < D_; ++i) acc += xs[i] * W[i * D_ + d];
      if (mat == 0) {
        qs[d] = acc * 0.25f;  // 1/sqrt(DH)
      } else if (mat == 1) {
        float kk = acc + SIGMA_ * eps_k[bp * D_ + d];
        ks[d] = kk;
        kw[bp * D_ + d] = kk;  // gather needs row t
      } else {
        float vv = acc + SIGMA_ * eps_v[bp * D_ + d];
        vs[d] = vv;
        vw[bp * D_ + d] = vv;
      }
    }
  }
  __syncthreads();

  // ---- attention: 8 waves x 2 rows = 16 s-slots, float4 lanes ----
  {
    int wave = tid >> 6;
    int lane = tid & 63;
    int row = lane >> 5;
    int lr = lane & 31;        // float4 index within the 128-float row
    int w16 = wave * 2 + row;  // slot 0..15
    const f4* Kb = (const f4*)(K + (size_t)bp * S_ * D_);
    const f4* Vb = (const f4*)(V + (size_t)bp * S_ * D_);
    f4 qv = *(const f4*)(qs + 4 * lr);
    float m = -1e30f, l = 0.f;
    f4 acc = {0.f, 0.f, 0.f, 0.f};
    const int RD4 = D_ / 4;  // 32
    for (int s = w16; s <= t; s += 16) {
      f4 kk, vv;
      if (s == t) {
        kk = *(const f4*)(ks + 4 * lr);
        vv = *(const f4*)(vs + 4 * lr);
      } else {
        kk = Kb[(size_t)s * RD4 + lr];
        vv = Vb[(size_t)s * RD4 + lr];
      }
      float p = qv.x * kk.x + qv.y * kk.y + qv.z * kk.z + qv.w * kk.w;
      p += __shfl_xor(p, 1);
      p += __shfl_xor(p, 2);  // quad holds score for head lr>>2
      float mnew = fmaxf(m, p);
      float scale = expf(m - mnew);
      float e = expf(p - mnew);
      l = l * scale + e;
      acc.x = acc.x * scale + e * vv.x;
      acc.y = acc.y * scale + e * vv.y;
      acc.z = acc.z * scale + e * vv.z;
      acc.w = acc.w * scale + e * vv.w;
      m = mnew;
    }
    *(f4*)(&accs[w16][4 * lr]) = acc;
    if ((lr & 3) == 0) { ms[w16][lr >> 2] = m; ls[w16][lr >> 2] = l; }
  }
  __syncthreads();

  // ---- merge 16 slots -> ctx (stays in LDS) ----
  if (tid < D_) {
    int h = tid >> 4;
    float mg = -1e30f;
    for (int w2 = 0; w2 < 16; ++w2) mg = fmaxf(mg, ms[w2][h]);
    float L = 0.f, C = 0.f;
    for (int w2 = 0; w2 < 16; ++w2) {
      float sc = expf(ms[w2][h] - mg);
      L += ls[w2][h] * sc;
      C += accs[w2][tid] * sc;
    }
    cs[tid] = C / L;
  }
  __syncthreads();

  // ---- head: all 512 threads in every dot ----
  int d = tid & 127;
  int qq = tid >> 7;
  {  // z = ctx @ Wo : quarter-split over i
    float acc = 0.f;
    int i0 = qq * 32;
    for (int i = i0; i < i0 + 32; ++i) acc += cs[i] * Wo[i * D_ + d];
    part[qq][d] = acc;
  }
  __syncthreads();
  if (tid < D_) {
    float z = part[0][tid] + part[1][tid] + part[2][tid] + part[3][tid] +
              SIGMA_ * eps_z[bp * D_ + tid];
    zs[tid] = z;
    out_z[bp * D_ + tid] = z;
  }
  __syncthreads();
  {  // a = relu(z @ W1 + b1)
    float acc = b1[tid];
    for (int i = 0; i < D_; ++i) acc += zs[i] * W1[i * DFF_ + tid];
    as_[tid] = fmaxf(acc, 0.f);
  }
  __syncthreads();
  {  // r = a @ W2 + b2 : quarter-split over j
    float acc = 0.f;
    int j0 = qq * 128;
    for (int j = j0; j < j0 + 128; ++j) acc += as_[j] * W2[j * D_ + d];
    part[qq][d] = acc;
  }
  __syncthreads();
  if (tid < D_) {
    float r = part[0][tid] + part[1][tid] + part[2][tid] + part[3][tid] + b2[tid];
    rs[tid] = r;
    out_r[bp * D_ + tid] = r;
  }
  __syncthreads();
  if (tid < 64) {
    float acc = rs[tid] * Wout[tid] + rs[tid + 64] * Wout[tid + 64];
    acc += __shfl_xor(acc, 1);
    acc += __shfl_xor(acc, 2);
    acc += __shfl_xor(acc, 4);
    acc += __shfl_xor(acc, 8);
    acc += __shfl_xor(acc, 16);
    acc += __shfl_xor(acc, 32);
    if (tid == 0) out_pred[bp] = acc + bout[0];
  }
}

// ---------------- K2: weights + threefry categorical sampling ---------------
__device__ inline unsigned rotl_(unsigned x, int r) {
  return (x << r) | (x >> (32 - r));
}

__device__ inline void threefry2x32_(unsigned x0, unsigned x1, unsigned& o0,
                                     unsigned& o1) {
  const unsigned k0 = 0u, k1 = 42u;
  const unsigned k2 = k0 ^ k1 ^ 0x1BD11BDAu;
  x0 += k0; x1 += k1;
#define RND_(r) { x0 += x1; x1 = rotl_(x1, r); x1 ^= x0; }
  RND_(13) RND_(15) RND_(26) RND_(6)   x0 += k1; x1 += k2 + 1u;
  RND_(17) RND_(29) RND_(16) RND_(24)  x0 += k2; x1 += k0 + 2u;
  RND_(13) RND_(15) RND_(26) RND_(6)   x0 += k0; x1 += k1 + 3u;
  RND_(17) RND_(29) RND_(16) RND_(24)  x0 += k1; x1 += k2 + 4u;
  RND_(13) RND_(15) RND_(26) RND_(6)   x0 += k2; x1 += k0 + 5u;
#undef RND_
  o0 = x0; o1 = x1;
}

__device__ inline float gumbel_at_(int n) {
  unsigned o0, o1;
  threefry2x32_(0u, (unsigned)n, o0, o1);
  unsigned bits = o0 ^ o1;
  unsigned fb = (bits >> 9) | 0x3f800000u;
  float f = __uint_as_float(fb) - 1.0f;
  const float tiny = 1.1754944e-38f;
  float u = fmaxf(tiny, f * (1.0f - tiny) + tiny);
  return -logf(-logf(u));
}

__global__ __launch_bounds__(64) void sample_kernel(
    const float* __restrict__ pred, const float* __restrict__ y,
    float* __restrict__ out_w, int* __restrict__ idx) {
  int b = blockIdx.x;  // 0..15
  int tid = threadIdx.x;
  __shared__ float lw[P_];
  __shared__ float logits[P_];
  __shared__ float red[2];
  if (tid < P_) {
    float mu = y[b * 4] - pred[b * P_ + tid];
    lw[tid] = -0.25f * (mu * mu);  // -0.5*OMEGA
  }
  __syncthreads();
  if (tid == 0) {
    float mn = lw[0];
    for (int p = 1; p < P_; ++p) mn = fminf(mn, lw[p]);
    red[0] = mn;
  }
  __syncthreads();
  if (tid < P_) lw[tid] = expf(lw[tid] - red[0]);
  __syncthreads();
  if (tid == 0) {
    float s = 0.f;
    for (int p = 0; p < P_; ++p) s += lw[p];
    red[1] = s;
  }
  __syncthreads();
  if (tid < P_) {
    float wn = lw[tid] / red[1];
    out_w[b * P_ + tid] = wn;
    logits[tid] = logf(wn + 1e-10f);
  }
  __syncthreads();
  if (tid < P_) {
    float best = -1e30f;
    int bestj = 0;
    for (int j = 0; j < P_; ++j) {
      int n = (b * P_ + tid) * P_ + j;
      float val = gumbel_at_(n) + logits[j];
      if (val > best) { best = val; bestj = j; }  // first-index tie-break
    }
    idx[b * P_ + tid] = bestj;
  }
}

// ---------------- K3: gather K_res / V_res + I_new (fused) ------------------
__global__ __launch_bounds__(256) void gather_kernel(
    const float* __restrict__ K, const float* __restrict__ V,
    const float* __restrict__ kn, const float* __restrict__ vn,
    const int* __restrict__ I, const int* __restrict__ idx,
    const int* __restrict__ tptr, float* __restrict__ outK,
    float* __restrict__ outV, float* __restrict__ outI) {
  const int CH = 4;                   // chunks per row
  const int F4 = (S_ * D_ / 4) / CH;  // 8192 float4 per chunk
  const int NG = B_ * P_ * CH * 2;    // 3200 gather blocks
  int bid = blockIdx.x;               // 0..3599
  int t = tptr[0];
  if (bid < NG) {
    int tv = bid / (B_ * P_ * CH);
    int rem = bid - tv * (B_ * P_ * CH);
    int bp = rem / CH;
    int chunk = rem - bp * CH;
    int b = bp / P_;
    int j = idx[bp];
    const float* src = (tv == 0 ? K : V) + (size_t)(b * P_ + j) * (S_ * D_);
    const f4* sub = (const f4*)((tv == 0 ? kn : vn) + (b * P_ + j) * D_);
    float* dst = (tv == 0 ? outK : outV) + (size_t)bp * (S_ * D_);
    const f4* src4 = (const f4*)src;
    f4* dst4 = (f4*)dst;
    int base = chunk * F4;
    int tlo = t * (D_ / 4);
    for (int i = base + threadIdx.x; i < base + F4; i += 256) {
      f4 val;
      if (i >= tlo && i < tlo + D_ / 4) val = sub[i - tlo];
      else                              val = src4[i];
      dst4[i] = val;
    }
  } else {
    // I_new (ints written as float values)
    int bp = bid - NG;
    int b = bp / P_;
    int j = idx[bp];
    const int* src = I + (b * P_ + j) * S_;
    float* dst = outI + bp * S_;
    for (int s = threadIdx.x; s < S_; s += 256) {
      int val = (s == t) ? j : src[s];
      dst[s] = (float)val;
    }
  }
}

extern "C" void kernel_launch(void* const* d_in, const int* in_sizes, int n_in,
                              void* d_out, int out_size, void* d_ws,
                              size_t ws_size, hipStream_t stream) {
  const float* x     = (const float*)d_in[0];
  const float* y     = (const float*)d_in[1];
  const float* K     = (const float*)d_in[2];
  const float* V     = (const float*)d_in[3];
  const int*   I     = (const int*)d_in[5];
  const float* Wq    = (const float*)d_in[6];
  const float* Wk    = (const float*)d_in[7];
  const float* Wv    = (const float*)d_in[8];
  const float* Wo    = (const float*)d_in[9];
  const float* W1    = (const float*)d_in[10];
  const float* b1    = (const float*)d_in[11];
  const float* W2    = (const float*)d_in[12];
  const float* b2    = (const float*)d_in[13];
  const float* Wout  = (const float*)d_in[14];
  const float* bout  = (const float*)d_in[15];
  const float* eps_k = (const float*)d_in[16];
  const float* eps_v = (const float*)d_in[17];
  const float* eps_z = (const float*)d_in[18];
  const int*   tptr  = (const int*)d_in[19];

  float* out      = (float*)d_out;
  float* out_r    = out;
  float* out_z    = out + 51200;
  float* out_pred = out + 102400;
  float* out_w    = out + 102800;
  float* outK     = out + 103200;
  float* outV     = outK + (size_t)52428800;
  float* outI     = outV + (size_t)52428800;

  float* ws  = (float*)d_ws;
  float* k   = ws;
  float* v   = ws + 51200;
  int*   idx = (int*)(ws + 102400);

  fused_kernel<<<B_ * P_, 512, 0, stream>>>(
      x, Wq, Wk, Wv, eps_k, eps_v, K, V, tptr, Wo, eps_z, W1, b1, W2, b2,
      Wout, bout, k, v, out_r, out_z, out_pred);
  sample_kernel<<<B_, 64, 0, stream>>>(out_pred, y, out_w, idx);
  gather_kernel<<<B_ * P_ * 4 * 2 + B_ * P_, 256, 0, stream>>>(
      K, V, k, v, I, idx, tptr, outK, outV, outI);
}